// Round 1
// baseline (219.723 us; speedup 1.0000x reference)
//
#include <hip/hip_runtime.h>
#include <hip/hip_bf16.h>
#include <math.h>

// Problem constants (from reference): B=128, N=2048, M=128
#define BB 128
#define NN 2048
#define MM 128
#define ROWS_PER_BLOCK 128   // n-rows handled per block in pass A
#define OFFSET_EPS 1e-6f
#define COS_EPS 1e-8f

// ---------------------------------------------------------------------------
// Pass A: one read of memory[B,N,M].
//  - score[b,n] = beta_b * cos(memory[b,n,:]+eps, k[b,:]+eps)
//  - colsum[b,m] += memory[b,n,m]   (raw memory, no eps — matches reference)
// Block = 256 threads = 4 waves. Each wave: lane owns columns (2*lane, 2*lane+1),
// iterates 32 rows; per-row 64-lane butterfly reduce for dot / sumsq.
// ---------------------------------------------------------------------------
__global__ __launch_bounds__(256) void pass_a(
    const float* __restrict__ memory, const float* __restrict__ k_t,
    const float* __restrict__ beta_t, float* __restrict__ colsum,
    float* __restrict__ score)
{
    const int blocks_per_b = NN / ROWS_PER_BLOCK;          // 16
    const int b     = blockIdx.x / blocks_per_b;
    const int r0    = (blockIdx.x % blocks_per_b) * ROWS_PER_BLOCK;
    const int wave  = threadIdx.x >> 6;
    const int lane  = threadIdx.x & 63;

    // k fragment for this lane's two columns (coalesced 512B per wave)
    float2 kraw = *(const float2*)(k_t + b * MM + 2 * lane);
    const float kx = kraw.x + OFFSET_EPS;
    const float ky = kraw.y + OFFSET_EPS;

    // nk = max(||k+eps||, COS_EPS)  (per-b scalar; every wave computes it)
    float nks = kx * kx + ky * ky;
    #pragma unroll
    for (int s = 32; s; s >>= 1) nks += __shfl_xor(nks, s);
    const float nk = fmaxf(sqrtf(nks), COS_EPS);
    const float beta_over_nk = beta_t[b] / nk;

    const float* mbase = memory + (size_t)b * NN * MM;
    float cs_x = 0.f, cs_y = 0.f;

    #pragma unroll 4
    for (int i = 0; i < ROWS_PER_BLOCK / 4; ++i) {
        const int n = r0 + wave + 4 * i;
        float2 mv = *(const float2*)(mbase + (size_t)n * MM + 2 * lane);
        cs_x += mv.x;                     // raw memory for colsum
        cs_y += mv.y;
        const float vx = mv.x + OFFSET_EPS;
        const float vy = mv.y + OFFSET_EPS;
        float dot = vx * kx + vy * ky;
        float sq  = vx * vx + vy * vy;
        #pragma unroll
        for (int s = 32; s; s >>= 1) {
            dot += __shfl_xor(dot, s);
            sq  += __shfl_xor(sq,  s);
        }
        if (lane == 0) {
            const float nm = fmaxf(sqrtf(sq), COS_EPS);
            score[b * NN + n] = dot * beta_over_nk / nm;
        }
    }

    // combine 4 waves' column partials in LDS, one atomicAdd per (b,m)
    __shared__ float s_col[4][MM];
    s_col[wave][2 * lane]     = cs_x;
    s_col[wave][2 * lane + 1] = cs_y;
    __syncthreads();
    if (threadIdx.x < MM) {
        const float v = s_col[0][threadIdx.x] + s_col[1][threadIdx.x] +
                        s_col[2][threadIdx.x] + s_col[3][threadIdx.x];
        atomicAdd(colsum + b * MM + threadIdx.x, v);
    }
}

// ---------------------------------------------------------------------------
// Pass B: per-b softmax + epilogue. One block (256 thr) per batch row.
// out[b, 0:M)      = r_t = S*((1-S*e)*colsum + N*S*a)
// out[b, M:M+N)    = w_t = S (broadcast)
// out[b, M+N:M+2N) = w_g = g*softmax + (1-g)*w_prev
// ---------------------------------------------------------------------------
__global__ __launch_bounds__(256) void pass_b(
    const float* __restrict__ score,  const float* __restrict__ g_t,
    const float* __restrict__ w_prev, const float* __restrict__ gamma_t,
    const float* __restrict__ e_t,    const float* __restrict__ a_t,
    const float* __restrict__ colsum, float* __restrict__ out)
{
    const int b   = blockIdx.x;
    const int tid = threadIdx.x;
    __shared__ float red[256];

    // ---- softmax over N=2048 (8 elems/thread) ----
    float sc[8];
    float mx = -INFINITY;
    #pragma unroll
    for (int i = 0; i < 8; ++i) {
        sc[i] = score[b * NN + tid + 256 * i];
        mx = fmaxf(mx, sc[i]);
    }
    red[tid] = mx; __syncthreads();
    for (int s = 128; s; s >>= 1) {
        if (tid < s) red[tid] = fmaxf(red[tid], red[tid + s]);
        __syncthreads();
    }
    mx = red[0]; __syncthreads();

    float sum = 0.f;
    #pragma unroll
    for (int i = 0; i < 8; ++i) {
        sc[i] = expf(sc[i] - mx);
        sum += sc[i];
    }
    red[tid] = sum; __syncthreads();
    for (int s = 128; s; s >>= 1) {
        if (tid < s) red[tid] += red[tid + s];
        __syncthreads();
    }
    const float inv_sum = 1.f / red[0];
    __syncthreads();

    // ---- w_g and S = sum(w_prev^gamma) + eps ----
    const float g     = g_t[b];
    const float gamma = gamma_t[b];
    float wg[8];
    float psum = 0.f;
    #pragma unroll
    for (int i = 0; i < 8; ++i) {
        const float w = w_prev[b * NN + tid + 256 * i];
        wg[i] = g * (sc[i] * inv_sum) + (1.f - g) * w;
        psum += powf(w, gamma);
    }
    red[tid] = psum; __syncthreads();
    for (int s = 128; s; s >>= 1) {
        if (tid < s) red[tid] += red[tid + s];
        __syncthreads();
    }
    const float S = red[0] + OFFSET_EPS;

    // ---- writes ----
    float* orow = out + (size_t)b * (MM + 2 * NN);
    #pragma unroll
    for (int i = 0; i < 8; ++i) {
        const int n = tid + 256 * i;
        orow[MM + n]      = S;      // w_t broadcast
        orow[MM + NN + n] = wg[i];  // w_g
    }
    if (tid < MM) {
        const float cs = colsum[b * MM + tid];
        const float r  = S * ((1.f - S * e_t[b * MM + tid]) * cs +
                              (float)NN * S * a_t[b * MM + tid]);
        orow[tid] = r;
    }
}

extern "C" void kernel_launch(void* const* d_in, const int* in_sizes, int n_in,
                              void* d_out, int out_size, void* d_ws, size_t ws_size,
                              hipStream_t stream) {
    const float* memory  = (const float*)d_in[0];
    const float* k_t     = (const float*)d_in[1];
    const float* beta_t  = (const float*)d_in[2];
    const float* g_t     = (const float*)d_in[3];
    const float* w_prev  = (const float*)d_in[4];
    // d_in[5] = s_t (unused by the live output chains)
    const float* gamma_t = (const float*)d_in[6];
    const float* e_t     = (const float*)d_in[7];
    const float* a_t     = (const float*)d_in[8];
    float* out = (float*)d_out;

    // workspace layout: [colsum B*M | score B*N]
    float* colsum = (float*)d_ws;
    float* score  = colsum + BB * MM;

    hipMemsetAsync(colsum, 0, BB * MM * sizeof(float), stream);

    const int grid_a = BB * (NN / ROWS_PER_BLOCK);  // 2048 blocks
    pass_a<<<grid_a, 256, 0, stream>>>(memory, k_t, beta_t, colsum, score);
    pass_b<<<BB, 256, 0, stream>>>(score, g_t, w_prev, gamma_t, e_t, a_t,
                                   colsum, out);
}

// Round 2
// 214.736 us; speedup vs baseline: 1.0232x; 1.0232x over previous
//
#include <hip/hip_runtime.h>
#include <hip/hip_bf16.h>
#include <math.h>

// Problem constants (from reference): B=128, N=2048, M=128
#define BB 128
#define NN 2048
#define MM 128
#define ROWS_PER_BLOCK 128   // n-rows handled per block in pass A
#define CHUNKS (NN / ROWS_PER_BLOCK)   // 16 blocks per batch row
#define OFFSET_EPS 1e-6f
#define COS_EPS 1e-8f

// ---------------------------------------------------------------------------
// Pass A: one read of memory[B,N,M].
//   score[b,n]       = beta_b * cos(memory[b,n,:]+eps, k[b,:]+eps)
//   colsum_part[c,b,m] = partial column sums of raw memory for n-chunk c
// Block = 256 threads = 4 waves. Each lane loads float4 (16B); a row of
// M=128 floats = 32 lanes, so each wave covers 2 rows per iteration and the
// wave's 1KB load is fully contiguous. Row-reduction = 5 butterfly steps
// within each 32-lane half (vs 6 steps over 64 lanes at 8B in R0 — 2.4x
// fewer shuffle-ops/byte; this was the latency bottleneck).
// ---------------------------------------------------------------------------
__global__ __launch_bounds__(256) void pass_a(
    const float* __restrict__ memory, const float* __restrict__ k_t,
    const float* __restrict__ beta_t, float* __restrict__ colsum_part,
    float* __restrict__ score)
{
    const int b     = blockIdx.x / CHUNKS;
    const int chunk = blockIdx.x % CHUNKS;
    const int r0    = chunk * ROWS_PER_BLOCK;
    const int wave  = threadIdx.x >> 6;
    const int lane  = threadIdx.x & 63;
    const int half  = lane >> 5;   // which row of the wave's pair
    const int l32   = lane & 31;   // column group (4 cols each)

    // k fragment for this lane's 4 columns
    float4 kv = *(const float4*)(k_t + b * MM + 4 * l32);
    const float k0 = kv.x + OFFSET_EPS, k1 = kv.y + OFFSET_EPS,
                k2 = kv.z + OFFSET_EPS, k3 = kv.w + OFFSET_EPS;

    // nk = max(||k+eps||, COS_EPS): 5-step reduce within each 32-lane half
    float nks = k0 * k0 + k1 * k1 + k2 * k2 + k3 * k3;
    #pragma unroll
    for (int s = 16; s; s >>= 1) nks += __shfl_xor(nks, s);
    const float nk = fmaxf(sqrtf(nks), COS_EPS);
    const float beta_over_nk = beta_t[b] / nk;

    const float* mbase = memory + (size_t)b * NN * MM;
    float cs0 = 0.f, cs1 = 0.f, cs2 = 0.f, cs3 = 0.f;

    // wave w, iter i handles rows r0 + 8*i + 2*w + half
    #pragma unroll 4
    for (int i = 0; i < ROWS_PER_BLOCK / 8; ++i) {   // 16 iters
        const int n = r0 + 8 * i + 2 * wave + half;
        float4 mv = *(const float4*)(mbase + (size_t)n * MM + 4 * l32);
        cs0 += mv.x; cs1 += mv.y; cs2 += mv.z; cs3 += mv.w;  // raw for colsum
        const float v0 = mv.x + OFFSET_EPS, v1 = mv.y + OFFSET_EPS,
                    v2 = mv.z + OFFSET_EPS, v3 = mv.w + OFFSET_EPS;
        float dot = v0 * k0 + v1 * k1 + v2 * k2 + v3 * k3;
        float sq  = v0 * v0 + v1 * v1 + v2 * v2 + v3 * v3;
        #pragma unroll
        for (int s = 16; s; s >>= 1) {   // xor stays within each 32-lane half
            dot += __shfl_xor(dot, s);
            sq  += __shfl_xor(sq,  s);
        }
        if (l32 == 0) {
            const float nm = fmaxf(sqrtf(sq), COS_EPS);
            score[b * NN + n] = dot * beta_over_nk / nm;
        }
    }

    // combine 8 half-waves' column partials in LDS; write per-chunk partial
    // (no atomics, no zero-init dispatch needed)
    __shared__ float s_col[8][MM];
    const int hw = wave * 2 + half;
    s_col[hw][4 * l32 + 0] = cs0;
    s_col[hw][4 * l32 + 1] = cs1;
    s_col[hw][4 * l32 + 2] = cs2;
    s_col[hw][4 * l32 + 3] = cs3;
    __syncthreads();
    if (threadIdx.x < MM) {
        float v = 0.f;
        #pragma unroll
        for (int j = 0; j < 8; ++j) v += s_col[j][threadIdx.x];
        colsum_part[(size_t)chunk * BB * MM + b * MM + threadIdx.x] = v;
    }
}

// ---------------------------------------------------------------------------
// Pass B: per-b softmax + epilogue. One block (256 thr) per batch row.
// out[b, 0:M)      = r_t = S*((1-S*e)*colsum + N*S*a)
// out[b, M:M+N)    = w_t = S (broadcast)
// out[b, M+N:M+2N) = w_g = g*softmax + (1-g)*w_prev
// ---------------------------------------------------------------------------
__global__ __launch_bounds__(256) void pass_b(
    const float* __restrict__ score,  const float* __restrict__ g_t,
    const float* __restrict__ w_prev, const float* __restrict__ gamma_t,
    const float* __restrict__ e_t,    const float* __restrict__ a_t,
    const float* __restrict__ colsum_part, float* __restrict__ out)
{
    const int b   = blockIdx.x;
    const int tid = threadIdx.x;
    __shared__ float red[256];

    // ---- softmax over N=2048 (8 elems/thread) ----
    float sc[8];
    float mx = -INFINITY;
    #pragma unroll
    for (int i = 0; i < 8; ++i) {
        sc[i] = score[b * NN + tid + 256 * i];
        mx = fmaxf(mx, sc[i]);
    }
    red[tid] = mx; __syncthreads();
    for (int s = 128; s; s >>= 1) {
        if (tid < s) red[tid] = fmaxf(red[tid], red[tid + s]);
        __syncthreads();
    }
    mx = red[0]; __syncthreads();

    float sum = 0.f;
    #pragma unroll
    for (int i = 0; i < 8; ++i) {
        sc[i] = __expf(sc[i] - mx);
        sum += sc[i];
    }
    red[tid] = sum; __syncthreads();
    for (int s = 128; s; s >>= 1) {
        if (tid < s) red[tid] += red[tid + s];
        __syncthreads();
    }
    const float inv_sum = 1.f / red[0];
    __syncthreads();

    // ---- w_g and S = sum(w_prev^gamma) + eps ----
    const float g     = g_t[b];
    const float gamma = gamma_t[b];
    float wg[8];
    float psum = 0.f;
    #pragma unroll
    for (int i = 0; i < 8; ++i) {
        const float w = w_prev[b * NN + tid + 256 * i];
        wg[i] = g * (sc[i] * inv_sum) + (1.f - g) * w;
        psum += __powf(w, gamma);   // w in [0,1): __powf(0,g)=0, safe
    }
    red[tid] = psum; __syncthreads();
    for (int s = 128; s; s >>= 1) {
        if (tid < s) red[tid] += red[tid + s];
        __syncthreads();
    }
    const float S = red[0] + OFFSET_EPS;

    // ---- writes ----
    float* orow = out + (size_t)b * (MM + 2 * NN);
    #pragma unroll
    for (int i = 0; i < 8; ++i) {
        const int n = tid + 256 * i;
        orow[MM + n]      = S;      // w_t broadcast
        orow[MM + NN + n] = wg[i];  // w_g
    }
    if (tid < MM) {
        float cs = 0.f;
        #pragma unroll
        for (int c = 0; c < CHUNKS; ++c)
            cs += colsum_part[(size_t)c * BB * MM + b * MM + tid];
        const float r = S * ((1.f - S * e_t[b * MM + tid]) * cs +
                             (float)NN * S * a_t[b * MM + tid]);
        orow[tid] = r;
    }
}

extern "C" void kernel_launch(void* const* d_in, const int* in_sizes, int n_in,
                              void* d_out, int out_size, void* d_ws, size_t ws_size,
                              hipStream_t stream) {
    const float* memory  = (const float*)d_in[0];
    const float* k_t     = (const float*)d_in[1];
    const float* beta_t  = (const float*)d_in[2];
    const float* g_t     = (const float*)d_in[3];
    const float* w_prev  = (const float*)d_in[4];
    // d_in[5] = s_t (unused by the live output chains)
    const float* gamma_t = (const float*)d_in[6];
    const float* e_t     = (const float*)d_in[7];
    const float* a_t     = (const float*)d_in[8];
    float* out = (float*)d_out;

    // workspace layout: [colsum_part CHUNKS*B*M | score B*N]
    float* colsum_part = (float*)d_ws;
    float* score       = colsum_part + CHUNKS * BB * MM;

    const int grid_a = BB * CHUNKS;  // 2048 blocks
    pass_a<<<grid_a, 256, 0, stream>>>(memory, k_t, beta_t, colsum_part, score);
    pass_b<<<BB, 256, 0, stream>>>(score, g_t, w_prev, gamma_t, e_t, a_t,
                                   colsum_part, out);
}

// Round 3
// 213.166 us; speedup vs baseline: 1.0308x; 1.0074x over previous
//
#include <hip/hip_runtime.h>
#include <hip/hip_bf16.h>
#include <math.h>

// Problem constants (from reference): B=128, N=2048, M=128
#define BB 128
#define NN 2048
#define MM 128
#define ROWS 128                      // n-rows per block in pass A
#define CHUNKS (NN / ROWS)            // 16 blocks per batch row
#define STRIDE (MM + 4)               // 132 words: every row 16B-aligned
#define OFFSET_EPS 1e-6f
#define COS_EPS 1e-8f

// ---------------------------------------------------------------------------
// Pass A v3: one coalesced read of memory[B,N,M], NO cross-lane ops in the
// streaming path.
//   phase 1 (staging): 256 threads x 16 iters of float4 global->LDS tile,
//     colsum partials accumulated in registers (thread's column group is
//     iteration-invariant).
//   phase 2: thread t reduces half-row (r=t>>1, h=t&1) serially from LDS
//     (16x ds_read_b128), single __shfl_xor(1) pair combine.
//   eps folded algebraically: dot = Sum v*k' + eps*K1 (k'=k+eps),
//     nm^2 = Sum v^2 + 2*eps*Sum v + M*eps^2.
// LDS: 128*132*4 + 512 + 4096 + 8 = ~72 KB -> 2 blocks/CU.
// ---------------------------------------------------------------------------
__global__ __launch_bounds__(256) void pass_a(
    const float* __restrict__ memory, const float* __restrict__ k_t,
    const float* __restrict__ beta_t, float* __restrict__ colsum_part,
    float* __restrict__ score)
{
    __shared__ float tile[ROWS * STRIDE];
    __shared__ float ks[MM];          // k + eps
    __shared__ float s_col[8][MM];    // per-thread-group colsum partials
    __shared__ float s_bon;           // beta / nk
    __shared__ float s_epsK1;         // eps * Sum(k+eps)

    const int b     = blockIdx.x / CHUNKS;
    const int chunk = blockIdx.x % CHUNKS;
    const int r0    = chunk * ROWS;
    const int t     = threadIdx.x;

    // ---- k' staging + per-b constants (wave-0 lanes 0..31) ----
    if (t < 32) {
        float4 kv = *(const float4*)(k_t + b * MM + 4 * t);
        const float e0 = kv.x + OFFSET_EPS, e1 = kv.y + OFFSET_EPS,
                    e2 = kv.z + OFFSET_EPS, e3 = kv.w + OFFSET_EPS;
        *(float4*)&ks[4 * t] = make_float4(e0, e1, e2, e3);
        float s2 = e0 * e0 + e1 * e1 + e2 * e2 + e3 * e3;
        float s1 = e0 + e1 + e2 + e3;
        #pragma unroll
        for (int s = 16; s; s >>= 1) {
            s2 += __shfl_xor(s2, s);
            s1 += __shfl_xor(s1, s);
        }
        if (t == 0) {
            s_bon   = beta_t[b] / fmaxf(sqrtf(s2), COS_EPS);
            s_epsK1 = OFFSET_EPS * s1;
        }
    }

    // ---- phase 1: coalesced staging + colsum register partials ----
    const float* src = memory + (size_t)(b * NN + r0) * MM;
    float cs0 = 0.f, cs1 = 0.f, cs2 = 0.f, cs3 = 0.f;
    #pragma unroll
    for (int i = 0; i < 16; ++i) {
        float4 v = *(const float4*)(src + i * 1024 + 4 * t);
        cs0 += v.x; cs1 += v.y; cs2 += v.z; cs3 += v.w;   // raw memory
        const int row = i * 8 + (t >> 5);
        const int col = (4 * t) & 127;
        *(float4*)&tile[row * STRIDE + col] = v;
    }
    *(float4*)&s_col[t >> 5][(4 * t) & 127] = make_float4(cs0, cs1, cs2, cs3);
    __syncthreads();

    // ---- phase 2: serial half-row reduce from LDS (no shuffles in loop) ----
    const int r = t >> 1;
    const int h = t & 1;
    const float* vrow = &tile[r * STRIDE + h * 64];
    const float* krow = &ks[h * 64];
    float dot = 0.f, sq = 0.f, rs = 0.f;
    #pragma unroll
    for (int j = 0; j < 16; ++j) {
        float4 v = *(const float4*)(vrow + 4 * j);
        float4 k = *(const float4*)(krow + 4 * j);
        dot += v.x * k.x + v.y * k.y + v.z * k.z + v.w * k.w;
        sq  += v.x * v.x + v.y * v.y + v.z * v.z + v.w * v.w;
        rs  += v.x + v.y + v.z + v.w;
    }
    dot += __shfl_xor(dot, 1);
    sq  += __shfl_xor(sq, 1);
    rs  += __shfl_xor(rs, 1);
    if (h == 0) {
        const float d   = dot + s_epsK1;
        const float nm2 = sq + 2.0f * OFFSET_EPS * rs
                          + (float)MM * OFFSET_EPS * OFFSET_EPS;
        const float nm  = fmaxf(sqrtf(nm2), COS_EPS);
        score[b * NN + r0 + r] = d * s_bon / nm;
    }

    // ---- colsum combine: one column per thread (threads 0..127) ----
    if (t < MM) {
        float v = 0.f;
        #pragma unroll
        for (int g = 0; g < 8; ++g) v += s_col[g][t];
        colsum_part[(size_t)chunk * (BB * MM) + b * MM + t] = v;
    }
}

// ---------------------------------------------------------------------------
// Pass B: per-b softmax + epilogue. One block (256 thr) per batch row.
// out[b, 0:M)      = r_t = S*((1-S*e)*colsum + N*S*a)
// out[b, M:M+N)    = w_t = S (broadcast)
// out[b, M+N:M+2N) = w_g = g*softmax + (1-g)*w_prev
// ---------------------------------------------------------------------------
__global__ __launch_bounds__(256) void pass_b(
    const float* __restrict__ score,  const float* __restrict__ g_t,
    const float* __restrict__ w_prev, const float* __restrict__ gamma_t,
    const float* __restrict__ e_t,    const float* __restrict__ a_t,
    const float* __restrict__ colsum_part, float* __restrict__ out)
{
    const int b   = blockIdx.x;
    const int tid = threadIdx.x;
    __shared__ float red[256];

    // ---- softmax over N=2048 (8 elems/thread) ----
    float sc[8];
    float mx = -INFINITY;
    #pragma unroll
    for (int i = 0; i < 8; ++i) {
        sc[i] = score[b * NN + tid + 256 * i];
        mx = fmaxf(mx, sc[i]);
    }
    red[tid] = mx; __syncthreads();
    for (int s = 128; s; s >>= 1) {
        if (tid < s) red[tid] = fmaxf(red[tid], red[tid + s]);
        __syncthreads();
    }
    mx = red[0]; __syncthreads();

    float sum = 0.f;
    #pragma unroll
    for (int i = 0; i < 8; ++i) {
        sc[i] = __expf(sc[i] - mx);
        sum += sc[i];
    }
    red[tid] = sum; __syncthreads();
    for (int s = 128; s; s >>= 1) {
        if (tid < s) red[tid] += red[tid + s];
        __syncthreads();
    }
    const float inv_sum = 1.f / red[0];
    __syncthreads();

    // ---- w_g and S = sum(w_prev^gamma) + eps ----
    const float g     = g_t[b];
    const float gamma = gamma_t[b];
    float wg[8];
    float psum = 0.f;
    #pragma unroll
    for (int i = 0; i < 8; ++i) {
        const float w = w_prev[b * NN + tid + 256 * i];
        wg[i] = g * (sc[i] * inv_sum) + (1.f - g) * w;
        psum += __powf(w, gamma);   // w in [0,1): safe
    }
    red[tid] = psum; __syncthreads();
    for (int s = 128; s; s >>= 1) {
        if (tid < s) red[tid] += red[tid + s];
        __syncthreads();
    }
    const float S = red[0] + OFFSET_EPS;

    // ---- writes ----
    float* orow = out + (size_t)b * (MM + 2 * NN);
    #pragma unroll
    for (int i = 0; i < 8; ++i) {
        const int n = tid + 256 * i;
        orow[MM + n]      = S;      // w_t broadcast
        orow[MM + NN + n] = wg[i];  // w_g
    }
    if (tid < MM) {
        float cs = 0.f;
        #pragma unroll
        for (int c = 0; c < CHUNKS; ++c)
            cs += colsum_part[(size_t)c * (BB * MM) + b * MM + tid];
        const float r = S * ((1.f - S * e_t[b * MM + tid]) * cs +
                             (float)NN * S * a_t[b * MM + tid]);
        orow[tid] = r;
    }
}

extern "C" void kernel_launch(void* const* d_in, const int* in_sizes, int n_in,
                              void* d_out, int out_size, void* d_ws, size_t ws_size,
                              hipStream_t stream) {
    const float* memory  = (const float*)d_in[0];
    const float* k_t     = (const float*)d_in[1];
    const float* beta_t  = (const float*)d_in[2];
    const float* g_t     = (const float*)d_in[3];
    const float* w_prev  = (const float*)d_in[4];
    // d_in[5] = s_t (unused by the live output chains)
    const float* gamma_t = (const float*)d_in[6];
    const float* e_t     = (const float*)d_in[7];
    const float* a_t     = (const float*)d_in[8];
    float* out = (float*)d_out;

    // workspace layout: [colsum_part CHUNKS*B*M | score B*N]
    float* colsum_part = (float*)d_ws;
    float* score       = colsum_part + CHUNKS * BB * MM;

    const int grid_a = BB * CHUNKS;  // 2048 blocks
    pass_a<<<grid_a, 256, 0, stream>>>(memory, k_t, beta_t, colsum_part, score);
    pass_b<<<BB, 256, 0, stream>>>(score, g_t, w_prev, gamma_t, e_t, a_t,
                                   colsum_part, out);
}